// Round 12
// baseline (203.239 us; speedup 1.0000x reference)
//
#include <hip/hip_runtime.h>
#include <hip/hip_bf16.h>
#include <stdint.h>

#define KDIM    256
#define NWORDS  1564         // sign words per column (= gemm grid: 64-row stripes)
#define NW      1563         // crossing words (ceil(99999/64))

typedef float  f32x4  __attribute__((ext_vector_type(4)));
typedef __bf16 bf16x8 __attribute__((ext_vector_type(8)));
typedef __bf16 bf16x4 __attribute__((ext_vector_type(4)));

// ---------- K0: build W, tile-major (B is read direct-to-reg) ----------
__global__ void build_w(const float* __restrict__ theta,
                        const float* __restrict__ noise,
                        __bf16* __restrict__ Wt) {
    int idx = blockIdx.x * 256 + threadIdx.x;   // 0..262143
    int j = idx >> 9;
    int d = idx & 511;
    float v;
    if (j < KDIM) v = theta[j * 512 + d];
    else          v = theta[(j - KDIM) * 512 + d] + 0.01f * noise[(j - KDIM) * 512 + d];
    Wt[((d >> 5) * 512 + j) * 32 + (d & 31)] = (__bf16)v;
}

// ---------- K1: R10 structure (proven best) ----------
__global__ void __launch_bounds__(512, 4)
gemm_signs(const float* __restrict__ basis,
           const __bf16* __restrict__ Wt,
           uint64_t* __restrict__ sbits) {
    __shared__ char smem[34816];

    const int tid    = threadIdx.x;
    const int lane   = tid & 63;
    const int wc     = tid >> 6;
    const int lane16 = lane & 15;
    const int lgrp   = lane >> 4;

    const int orig = blockIdx.x;
    const int x    = orig & 7;
    const int bm   = (x < 4 ? x * 196 : 784 + (x - 4) * 195) + (orig >> 3);

    const int rl  = tid >> 3;
    const int oct = tid & 7;
    int r = bm * 64 + rl; if (r > 99999) r = 99999;
    const float* asrc = basis + (size_t)r * 512 + oct * 4;
    const int awofs = rl * 64 + (((oct >> 1) ^ ((rl >> 1) & 3)) << 4) + ((oct & 1) << 3);

    const char* wbase = (const char*)Wt;
    int bfofs[4];
    #pragma unroll
    for (int n = 0; n < 4; ++n)
        bfofs[n] = (wc * 64 + n * 16 + lane16) * 64 + lgrp * 16;

    f32x4  acc[4][4] = {};
    float4 ra[2];
    bf16x8 bf[2][4];

    ra[0] = *(const float4*)(asrc);
    ra[1] = *(const float4*)(asrc + 32);
    #pragma unroll
    for (int n = 0; n < 4; ++n)
        bf[0][n] = *(const bf16x8*)(wbase + bfofs[n]);
    {
        bf16x4 v;
        v[0] = (__bf16)ra[0].x; v[1] = (__bf16)ra[0].y;
        v[2] = (__bf16)ra[0].z; v[3] = (__bf16)ra[0].w;
        *(bf16x4*)(smem + awofs) = v;
    }
    asm volatile("s_waitcnt lgkmcnt(0)" ::: "memory");

    #pragma unroll
    for (int t = 0; t < 16; ++t) {
        if (t < 14) ra[t & 1] = *(const float4*)(asrc + (t + 2) * 32);
        if (t < 15) {
            #pragma unroll
            for (int n = 0; n < 4; ++n)
                bf[(t + 1) & 1][n] =
                    *(const bf16x8*)(wbase + (size_t)(t + 1) * 32768 + bfofs[n]);
        }

        __builtin_amdgcn_s_barrier();

        if (t < 15) {
            bf16x4 v;
            float4 rv = ra[(t + 1) & 1];
            v[0] = (__bf16)rv.x; v[1] = (__bf16)rv.y;
            v[2] = (__bf16)rv.z; v[3] = (__bf16)rv.w;
            *(bf16x4*)(smem + (((t + 1) & 1) << 12) + awofs) = v;
        }

        const char* ab = smem + ((t & 1) << 12);
        #pragma unroll
        for (int mh = 0; mh < 2; ++mh) {
            bf16x8 af[2];
            #pragma unroll
            for (int mi = 0; mi < 2; ++mi) {
                int rr = (mh * 2 + mi) * 16 + lane16;
                af[mi] = *(const bf16x8*)(ab + rr * 64
                           + ((lgrp ^ ((rr >> 1) & 3)) << 4));
            }
            asm volatile("s_waitcnt lgkmcnt(0)" ::: "memory");
            __builtin_amdgcn_sched_barrier(0);
            __builtin_amdgcn_s_setprio(1);
            #pragma unroll
            for (int mi = 0; mi < 2; ++mi)
                #pragma unroll
                for (int n = 0; n < 4; ++n)
                    acc[mh * 2 + mi][n] = __builtin_amdgcn_mfma_f32_16x16x32_bf16(
                        af[mi], bf[t & 1][n], acc[mh * 2 + mi][n], 0, 0, 0);
            __builtin_amdgcn_s_setprio(0);
        }
    }

    __builtin_amdgcn_s_barrier();
    unsigned char* sb = (unsigned char*)smem;     // [512 cols][68B]
    #pragma unroll
    for (int m = 0; m < 4; ++m) {
        #pragma unroll
        for (int n = 0; n < 4; ++n) {
            int cc = wc * 64 + n * 16 + lane16;
            int rb = m * 16 + lgrp * 4;
            uint32_t pk = 0;
            #pragma unroll
            for (int rg = 0; rg < 4; ++rg)
                pk |= (acc[m][n][rg] < 0.0f ? 1u : 0u) << (8 * rg);
            *(uint32_t*)&sb[cc * 68 + rb] = pk;
        }
    }
    asm volatile("s_waitcnt lgkmcnt(0)" ::: "memory");
    __builtin_amdgcn_s_barrier();

    {
        const unsigned char* src = &sb[tid * 68];
        uint64_t wbits = 0;
        #pragma unroll
        for (int k = 0; k < 16; ++k) {
            uint32_t qv = *(const uint32_t*)&src[4 * k];
            uint32_t p4 = ((qv & 0x01010101u) * 0x10204080u) >> 28;
            wbits |= (uint64_t)p4 << (4 * k);
        }
        sbits[(size_t)bm * 512 + tid] = wbits;
    }
}

// ---------- PROBE 1: the A-f32 load stream ALONE (same addresses as R10) ----
// No LDS, no barriers, no MFMA. Depth-4 register ring, sums kept live.
__global__ void __launch_bounds__(512, 4)
probe_astream(const float* __restrict__ basis, float* __restrict__ scr) {
    const int tid  = threadIdx.x;
    const int orig = blockIdx.x;
    const int x    = orig & 7;
    const int bm   = (x < 4 ? x * 196 : 784 + (x - 4) * 195) + (orig >> 3);

    const int rl  = tid >> 3;
    const int oct = tid & 7;
    int r = bm * 64 + rl; if (r > 99999) r = 99999;
    const float* ag = basis + (size_t)r * 512 + oct * 4;

    f32x4 ra[4];
    #pragma unroll
    for (int u = 0; u < 4; ++u) ra[u] = *(const f32x4*)(ag + u * 32);
    f32x4 s = {0.f, 0.f, 0.f, 0.f};
    #pragma unroll
    for (int t = 0; t < 16; ++t) {
        f32x4 v = ra[t & 3];
        if (t < 12) ra[t & 3] = *(const f32x4*)(ag + (t + 4) * 32);
        s += v;
    }
    scr[(size_t)blockIdx.x * 512 + tid] = s[0] + s[1] + s[2] + s[3];
}

// ---------- PROBE 2: R10 minus the A global loads (constant ds_writes) ------
// B loads, ds_reads, barriers, MFMA, epilogue all identical to gemm_signs.
__global__ void __launch_bounds__(512, 4)
probe_noa(const __bf16* __restrict__ Wt, uint64_t* __restrict__ scr) {
    __shared__ char smem[34816];

    const int tid    = threadIdx.x;
    const int lane   = tid & 63;
    const int wc     = tid >> 6;
    const int lane16 = lane & 15;
    const int lgrp   = lane >> 4;

    const int orig = blockIdx.x;
    const int x    = orig & 7;
    const int bm   = (x < 4 ? x * 196 : 784 + (x - 4) * 195) + (orig >> 3);

    const int rl  = tid >> 3;
    const int oct = tid & 7;
    const int awofs = rl * 64 + (((oct >> 1) ^ ((rl >> 1) & 3)) << 4) + ((oct & 1) << 3);

    const char* wbase = (const char*)Wt;
    int bfofs[4];
    #pragma unroll
    for (int n = 0; n < 4; ++n)
        bfofs[n] = (wc * 64 + n * 16 + lane16) * 64 + lgrp * 16;

    f32x4  acc[4][4] = {};
    bf16x8 bf[2][4];
    bf16x4 cv;
    cv[0] = (__bf16)(float)(tid & 7); cv[1] = (__bf16)1.0f;
    cv[2] = (__bf16)(float)(rl & 3);  cv[3] = (__bf16)-1.0f;

    #pragma unroll
    for (int n = 0; n < 4; ++n)
        bf[0][n] = *(const bf16x8*)(wbase + bfofs[n]);
    *(bf16x4*)(smem + awofs) = cv;
    asm volatile("s_waitcnt lgkmcnt(0)" ::: "memory");

    #pragma unroll
    for (int t = 0; t < 16; ++t) {
        if (t < 15) {
            #pragma unroll
            for (int n = 0; n < 4; ++n)
                bf[(t + 1) & 1][n] =
                    *(const bf16x8*)(wbase + (size_t)(t + 1) * 32768 + bfofs[n]);
        }

        __builtin_amdgcn_s_barrier();

        if (t < 15) *(bf16x4*)(smem + (((t + 1) & 1) << 12) + awofs) = cv;

        const char* ab = smem + ((t & 1) << 12);
        #pragma unroll
        for (int mh = 0; mh < 2; ++mh) {
            bf16x8 af[2];
            #pragma unroll
            for (int mi = 0; mi < 2; ++mi) {
                int rr = (mh * 2 + mi) * 16 + lane16;
                af[mi] = *(const bf16x8*)(ab + rr * 64
                           + ((lgrp ^ ((rr >> 1) & 3)) << 4));
            }
            asm volatile("s_waitcnt lgkmcnt(0)" ::: "memory");
            __builtin_amdgcn_sched_barrier(0);
            __builtin_amdgcn_s_setprio(1);
            #pragma unroll
            for (int mi = 0; mi < 2; ++mi)
                #pragma unroll
                for (int n = 0; n < 4; ++n)
                    acc[mh * 2 + mi][n] = __builtin_amdgcn_mfma_f32_16x16x32_bf16(
                        af[mi], bf[t & 1][n], acc[mh * 2 + mi][n], 0, 0, 0);
            __builtin_amdgcn_s_setprio(0);
        }
    }

    __builtin_amdgcn_s_barrier();
    unsigned char* sb = (unsigned char*)smem;
    #pragma unroll
    for (int m = 0; m < 4; ++m) {
        #pragma unroll
        for (int n = 0; n < 4; ++n) {
            int cc = wc * 64 + n * 16 + lane16;
            int rb = m * 16 + lgrp * 4;
            uint32_t pk = 0;
            #pragma unroll
            for (int rg = 0; rg < 4; ++rg)
                pk |= (acc[m][n][rg] < 0.0f ? 1u : 0u) << (8 * rg);
            *(uint32_t*)&sb[cc * 68 + rb] = pk;
        }
    }
    asm volatile("s_waitcnt lgkmcnt(0)" ::: "memory");
    __builtin_amdgcn_s_barrier();
    {
        const unsigned char* src = &sb[tid * 68];
        uint64_t wbits = 0;
        #pragma unroll
        for (int k = 0; k < 16; ++k) {
            uint32_t qv = *(const uint32_t*)&src[4 * k];
            uint32_t p4 = ((qv & 0x01010101u) * 0x10204080u) >> 28;
            wbits |= (uint64_t)p4 << (4 * k);
        }
        scr[(size_t)bm * 512 + tid] = wbits;
    }
}

// ---------- K2: crossing masks from sign bits ----------
__global__ void crossing_masks(const uint64_t* __restrict__ sbits,
                               uint64_t* __restrict__ maskT) {
    const int w = blockIdx.x;
    const int j = threadIdx.x;
    uint64_t s0r = sbits[(size_t)w * 512 + j];
    uint64_t s0p = sbits[(size_t)w * 512 + 256 + j];
    uint64_t s1r = sbits[(size_t)(w + 1) * 512 + j];
    uint64_t s1p = sbits[(size_t)(w + 1) * 512 + 256 + j];
    uint64_t cr = s0r ^ ((s0r >> 1) | (s1r << 63));
    uint64_t cp = s0p ^ ((s0p >> 1) | (s1p << 63));
    uint64_t m = cr & cp;
    if (w == NW - 1) m &= 0x7FFFFFFFull;
    maskT[(size_t)w * 256 + j] = m;
}

// ---------- K3: pairwise AND-popcount ----------
__global__ void zero_out(float* __restrict__ out) {
    int i = blockIdx.x * 256 + threadIdx.x;
    if (i < 32640) out[i] = 0.0f;
}

__global__ void pair_popcount(const uint64_t* __restrict__ maskT,
                              float* __restrict__ out) {
    const int i = blockIdx.x;
    const int c = blockIdx.y;
    const int j = threadIdx.x;
    if (j <= i) return;
    int w0 = c * 196;
    int w1 = w0 + 196; if (w1 > NW) w1 = NW;
    uint32_t sum = 0;
    #pragma unroll 4
    for (int w = w0; w < w1; ++w) {
        uint64_t mi = maskT[(size_t)w * 256 + i];
        uint64_t mj = maskT[(size_t)w * 256 + j];
        sum += (uint32_t)__popcll(mi & mj);
    }
    const size_t idx = (size_t)i * (2 * KDIM - i - 1) / 2 + (size_t)(j - i - 1);
    atomicAdd(&out[idx], (float)sum);
}

extern "C" void kernel_launch(void* const* d_in, const int* in_sizes, int n_in,
                              void* d_out, int out_size, void* d_ws, size_t ws_size,
                              hipStream_t stream) {
    const float* theta = (const float*)d_in[0];
    const float* basis = (const float*)d_in[1];
    const float* noise = (const float*)d_in[2];
    float* out = (float*)d_out;

    char* ws = (char*)d_ws;
    __bf16*   Wt    = (__bf16*)ws;                              // 512 KB
    uint64_t* sbits = (uint64_t*)(ws + 524288);                 // 6.41 MB
    uint64_t* maskT = (uint64_t*)(ws + 524288 + (size_t)NWORDS * 512 * 8);
    float*    scr1  = (float*)(ws + (32u << 20));               // probe scratch
    uint64_t* scr2  = (uint64_t*)(ws + (48u << 20));

    hipLaunchKernelGGL(build_w,        dim3(1024),    dim3(256), 0, stream, theta, noise, Wt);
    hipLaunchKernelGGL(gemm_signs,     dim3(NWORDS),  dim3(512), 0, stream, basis, Wt, sbits);
    hipLaunchKernelGGL(probe_astream,  dim3(NWORDS),  dim3(512), 0, stream, basis, scr1);
    hipLaunchKernelGGL(probe_noa,      dim3(NWORDS),  dim3(512), 0, stream, Wt, scr2);
    hipLaunchKernelGGL(crossing_masks, dim3(NW),      dim3(256), 0, stream, sbits, maskT);
    hipLaunchKernelGGL(zero_out,       dim3(128),     dim3(256), 0, stream, out);
    hipLaunchKernelGGL(pair_popcount,  dim3(KDIM, 8), dim3(256), 0, stream, maskT, out);
}

// Round 13
// 132.784 us; speedup vs baseline: 1.5306x; 1.5306x over previous
//
#include <hip/hip_runtime.h>
#include <hip/hip_bf16.h>
#include <stdint.h>

#define KDIM    256
#define NWORDS  1564         // sign words per column (= gemm grid: 64-row stripes)
#define NW      1563         // crossing words (ceil(99999/64))

typedef float  f32x4  __attribute__((ext_vector_type(4)));
typedef __bf16 bf16x8 __attribute__((ext_vector_type(8)));
typedef __bf16 bf16x4 __attribute__((ext_vector_type(4)));

// ---------- K0: build W, tile-major (B is read direct-to-reg) ----------
__global__ void build_w(const float* __restrict__ theta,
                        const float* __restrict__ noise,
                        __bf16* __restrict__ Wt) {
    int idx = blockIdx.x * 256 + threadIdx.x;   // 0..262143
    int j = idx >> 9;
    int d = idx & 511;
    float v;
    if (j < KDIM) v = theta[j * 512 + d];
    else          v = theta[(j - KDIM) * 512 + d] + 0.01f * noise[(j - KDIM) * 512 + d];
    Wt[((d >> 5) * 512 + j) * 32 + (d & 31)] = (__bf16)v;
}

// ---------- K1: producer/consumer MFMA GEMM -> packed sign bits ----------
// 640 threads = 10 waves. Waves 8,9: A-producers, free-running through a
// 4-slot LDS ring (slot = 4KB bf16 tile, R10's swizzled layout). Waves 0..7:
// consumers (64x64 col panel each), R10 fragment/MFMA path, B direct
// global->reg depth-2. NO s_barrier in the K-loop: produce/consume ordering
// via LDS flag atomics (ready[slot]: 2 producer increments per use;
// cons_done[slot]: 8 consumer increments per use). Decouples the A-fetch
// stream from the compute schedule -- producers keep the memory pipe
// saturated continuously instead of barrier-synchronized bursts.
__global__ void __launch_bounds__(640)
gemm_signs_pc(const float* __restrict__ basis,
              const __bf16* __restrict__ Wt,
              uint64_t* __restrict__ sbits) {
    __shared__ char smem[34848];   // ring [0,16K); sb [0,34816) post-loop; flags @34816

    const int tid    = threadIdx.x;
    const int lane   = tid & 63;
    const int wave   = tid >> 6;       // 0..9
    const int lane16 = lane & 15;
    const int lgrp   = lane >> 4;

    unsigned* ready     = (unsigned*)(smem + 34816);       // [4]
    unsigned* cons_done = (unsigned*)(smem + 34816 + 16);  // [4]
    if (tid < 8) ((unsigned*)(smem + 34816))[tid] = 0;
    __syncthreads();

    // bijective XCD swizzle: nwg=1564=8*195+4 (m204)
    const int orig = blockIdx.x;
    const int x    = orig & 7;
    const int bm   = (x < 4 ? x * 196 : 784 + (x - 4) * 195) + (orig >> 3);

    char* ring = smem;                 // 4 slots x 4096B

    if (wave < 8) {
        // ================= CONSUMER =================
        const int wc = wave;
        const char* wbase = (const char*)Wt;
        int bfofs[4];
        #pragma unroll
        for (int n = 0; n < 4; ++n)
            bfofs[n] = (wc * 64 + n * 16 + lane16) * 64 + lgrp * 16;

        f32x4  acc[4][4] = {};
        bf16x8 bf[2][4];
        #pragma unroll
        for (int n = 0; n < 4; ++n)
            bf[0][n] = *(const bf16x8*)(wbase + bfofs[n]);

        #pragma unroll
        for (int t = 0; t < 16; ++t) {
            if (t < 15) {              // B(t+1) depth-2 prefetch (independent)
                #pragma unroll
                for (int n = 0; n < 4; ++n)
                    bf[(t + 1) & 1][n] =
                        *(const bf16x8*)(wbase + (size_t)(t + 1) * 32768 + bfofs[n]);
            }
            const int slot = t & 3;
            const unsigned need = 2u * (unsigned)((t >> 2) + 1);
            while (__hip_atomic_load(&ready[slot], __ATOMIC_ACQUIRE,
                                     __HIP_MEMORY_SCOPE_WORKGROUP) < need)
                __builtin_amdgcn_s_sleep(1);

            const char* ab = ring + slot * 4096;
            bf16x8 af[4];
            #pragma unroll
            for (int m = 0; m < 4; ++m) {
                int rr = m * 16 + lane16;
                af[m] = *(const bf16x8*)(ab + rr * 64
                           + ((lgrp ^ ((rr >> 1) & 3)) << 4));
            }
            asm volatile("s_waitcnt lgkmcnt(0)" ::: "memory");  // af in regs
            if (lane == 0)             // release slot early (data is in regs)
                __hip_atomic_fetch_add(&cons_done[slot], 1u, __ATOMIC_RELEASE,
                                       __HIP_MEMORY_SCOPE_WORKGROUP);
            __builtin_amdgcn_sched_barrier(0);
            __builtin_amdgcn_s_setprio(1);
            #pragma unroll
            for (int m = 0; m < 4; ++m)
                #pragma unroll
                for (int n = 0; n < 4; ++n)
                    acc[m][n] = __builtin_amdgcn_mfma_f32_16x16x32_bf16(
                        af[m], bf[t & 1][n], acc[m][n], 0, 0, 0);
            __builtin_amdgcn_s_setprio(0);
        }

        __syncthreads();               // K-loop LDS done block-wide
        // sign bytes -> LDS transpose (C/D: col=lane&15, row=(lane>>4)*4+reg)
        unsigned char* sb = (unsigned char*)smem;   // [512 cols][68B]
        #pragma unroll
        for (int m = 0; m < 4; ++m) {
            #pragma unroll
            for (int n = 0; n < 4; ++n) {
                int cc = wc * 64 + n * 16 + lane16;
                int rb = m * 16 + lgrp * 4;
                uint32_t pk = 0;
                #pragma unroll
                for (int rg = 0; rg < 4; ++rg)
                    pk |= (acc[m][n][rg] < 0.0f ? 1u : 0u) << (8 * rg);
                *(uint32_t*)&sb[cc * 68 + rb] = pk;
            }
        }
        asm volatile("s_waitcnt lgkmcnt(0)" ::: "memory");
        __syncthreads();
    } else {
        // ================= PRODUCER =================
        const int ptid = tid - 512;    // 0..127
        const int oct  = ptid & 7;     // float4 slice within a row's 32 f32
        const int p    = ptid >> 3;    // base row 0..15 (rows p, p+16, p+32, p+48)
        int rbase[4];
        #pragma unroll
        for (int i = 0; i < 4; ++i) {
            int r = bm * 64 + p + 16 * i;
            rbase[i] = (r > 99999) ? 99999 : r;
        }
        const int aw0 = (p) * 64 + (((oct >> 1) ^ ((p >> 1) & 3)) << 4)
                        + ((oct & 1) << 3);     // +1024*i for row p+16i

        float4 ra[2][4];
        #pragma unroll
        for (int i = 0; i < 4; ++i)
            ra[0][i] = *(const float4*)(basis + (size_t)rbase[i] * 512 + oct * 4);

        #pragma unroll
        for (int t = 0; t < 16; ++t) {
            if (t < 15) {              // depth-2: issue t+1 loads now
                #pragma unroll
                for (int i = 0; i < 4; ++i)
                    ra[(t + 1) & 1][i] = *(const float4*)
                        (basis + (size_t)rbase[i] * 512 + (t + 1) * 32 + oct * 4);
            }
            const int slot = t & 3;
            const unsigned r = (unsigned)(t >> 2);
            if (r > 0) {
                const unsigned need = 8u * r;
                while (__hip_atomic_load(&cons_done[slot], __ATOMIC_ACQUIRE,
                                         __HIP_MEMORY_SCOPE_WORKGROUP) < need)
                    __builtin_amdgcn_s_sleep(1);
            }
            char* wb = ring + slot * 4096;
            #pragma unroll
            for (int i = 0; i < 4; ++i) {
                float4 rv = ra[t & 1][i];
                bf16x4 v;
                v[0] = (__bf16)rv.x; v[1] = (__bf16)rv.y;
                v[2] = (__bf16)rv.z; v[3] = (__bf16)rv.w;
                *(bf16x4*)(wb + aw0 + 1024 * i) = v;
            }
            asm volatile("s_waitcnt lgkmcnt(0)" ::: "memory");  // writes visible
            if (lane == 0)
                __hip_atomic_fetch_add(&ready[slot], 1u, __ATOMIC_RELEASE,
                                       __HIP_MEMORY_SCOPE_WORKGROUP);
        }

        __syncthreads();               // match consumer barrier 1
        __syncthreads();               // match consumer barrier 2
    }

    // pack: one thread per column; 64 sign bytes -> u64; word index = bm
    if (tid < 512) {
        const unsigned char* src = (const unsigned char*)smem + tid * 68;
        uint64_t wbits = 0;
        #pragma unroll
        for (int k = 0; k < 16; ++k) {
            uint32_t qv = *(const uint32_t*)&src[4 * k];
            uint32_t p4 = ((qv & 0x01010101u) * 0x10204080u) >> 28;
            wbits |= (uint64_t)p4 << (4 * k);
        }
        sbits[(size_t)bm * 512 + tid] = wbits;
    }
}

// ---------- K2: crossing masks from sign bits ----------
__global__ void crossing_masks(const uint64_t* __restrict__ sbits,
                               uint64_t* __restrict__ maskT) {
    const int w = blockIdx.x;
    const int j = threadIdx.x;
    uint64_t s0r = sbits[(size_t)w * 512 + j];
    uint64_t s0p = sbits[(size_t)w * 512 + 256 + j];
    uint64_t s1r = sbits[(size_t)(w + 1) * 512 + j];
    uint64_t s1p = sbits[(size_t)(w + 1) * 512 + 256 + j];
    uint64_t cr = s0r ^ ((s0r >> 1) | (s1r << 63));
    uint64_t cp = s0p ^ ((s0p >> 1) | (s1p << 63));
    uint64_t m = cr & cp;
    if (w == NW - 1) m &= 0x7FFFFFFFull;
    maskT[(size_t)w * 256 + j] = m;
}

// ---------- K3: pairwise AND-popcount ----------
__global__ void zero_out(float* __restrict__ out) {
    int i = blockIdx.x * 256 + threadIdx.x;
    if (i < 32640) out[i] = 0.0f;
}

__global__ void pair_popcount(const uint64_t* __restrict__ maskT,
                              float* __restrict__ out) {
    const int i = blockIdx.x;
    const int c = blockIdx.y;
    const int j = threadIdx.x;
    if (j <= i) return;
    int w0 = c * 196;
    int w1 = w0 + 196; if (w1 > NW) w1 = NW;
    uint32_t sum = 0;
    #pragma unroll 4
    for (int w = w0; w < w1; ++w) {
        uint64_t mi = maskT[(size_t)w * 256 + i];
        uint64_t mj = maskT[(size_t)w * 256 + j];
        sum += (uint32_t)__popcll(mi & mj);
    }
    const size_t idx = (size_t)i * (2 * KDIM - i - 1) / 2 + (size_t)(j - i - 1);
    atomicAdd(&out[idx], (float)sum);
}

extern "C" void kernel_launch(void* const* d_in, const int* in_sizes, int n_in,
                              void* d_out, int out_size, void* d_ws, size_t ws_size,
                              hipStream_t stream) {
    const float* theta = (const float*)d_in[0];
    const float* basis = (const float*)d_in[1];
    const float* noise = (const float*)d_in[2];
    float* out = (float*)d_out;

    char* ws = (char*)d_ws;
    __bf16*   Wt    = (__bf16*)ws;                              // 512 KB
    uint64_t* sbits = (uint64_t*)(ws + 524288);                 // 6.41 MB
    uint64_t* maskT = (uint64_t*)(ws + 524288 + (size_t)NWORDS * 512 * 8);

    hipLaunchKernelGGL(build_w,        dim3(1024),    dim3(256), 0, stream, theta, noise, Wt);
    hipLaunchKernelGGL(gemm_signs_pc,  dim3(NWORDS),  dim3(640), 0, stream, basis, Wt, sbits);
    hipLaunchKernelGGL(crossing_masks, dim3(NW),      dim3(256), 0, stream, sbits, maskT);
    hipLaunchKernelGGL(zero_out,       dim3(128),     dim3(256), 0, stream, out);
    hipLaunchKernelGGL(pair_popcount,  dim3(KDIM, 8), dim3(256), 0, stream, maskT, out);
}

// Round 14
// 129.947 us; speedup vs baseline: 1.5640x; 1.0218x over previous
//
#include <hip/hip_runtime.h>
#include <hip/hip_bf16.h>
#include <stdint.h>

#define KDIM    256
#define NWORDS  1564         // sign words per column (= gemm grid: 64-row stripes)
#define NW      1563         // crossing words (ceil(99999/64))

typedef float  f32x4  __attribute__((ext_vector_type(4)));
typedef __bf16 bf16x8 __attribute__((ext_vector_type(8)));
typedef __bf16 bf16x4 __attribute__((ext_vector_type(4)));

// ---------- K0: build W, tile-major (B is read direct-to-reg) ----------
// Wt[t][j][32 bf16]: K-tile t (32 elems), row j.
__global__ void build_w(const float* __restrict__ theta,
                        const float* __restrict__ noise,
                        __bf16* __restrict__ Wt) {
    int idx = blockIdx.x * 256 + threadIdx.x;   // 0..262143
    int j = idx >> 9;
    int d = idx & 511;
    float v;
    if (j < KDIM) v = theta[j * 512 + d];
    else          v = theta[(j - KDIM) * 512 + d] + 0.01f * noise[(j - KDIM) * 512 + d];
    Wt[((d >> 5) * 512 + j) * 32 + (d & 31)] = (__bf16)v;
}

// ---------- K1: two-phase MFMA GEMM -> packed sign bits ----------
// Tile 64(M) x 512(N), 512 threads = 8 waves (wave = 64x64 col panel).
// PHASE 1: stream the block's full 128KB A-tile LINEARLY (each wave-load is
//   1KB fully contiguous -- same access shape as the 7TB/s fillBuffer),
//   cvt f32->bf16, granule-XOR-swizzled ds_write; whole tile lands in 64KB
//   LDS. One __syncthreads().
// PHASE 2: 16 K-steps of {4x ds_read_b128 + B direct global->reg (depth 2,
//   L2-resident Wt) + 32 MFMA}, ZERO barriers, zero global-A -- waves
//   free-run. Inter-block overlap (2 blocks/CU by LDS) pipelines one
//   block's phase-1 memory under another's phase-2 compute.
__global__ void __launch_bounds__(512, 4)
gemm_signs(const float* __restrict__ basis,
           const __bf16* __restrict__ Wt,
           uint64_t* __restrict__ sbits) {
    __shared__ char smem[65536];   // A-tile bf16 [64r][1024B]; epilogue aliases

    const int tid    = threadIdx.x;
    const int lane   = tid & 63;
    const int wc     = tid >> 6;       // wave 0..7 = column panel
    const int lane16 = lane & 15;
    const int lgrp   = lane >> 4;

    // bijective XCD swizzle: nwg=1564=8*195+4 (m204)
    const int orig = blockIdx.x;
    const int x    = orig & 7;
    const int bm   = (x < 4 ? x * 196 : 784 + (x - 4) * 195) + (orig >> 3);  // 0..1563

    // ---- B fragment addressing (direct global, tile-major) ----
    const char* wbase = (const char*)Wt;
    int bfofs[4];
    #pragma unroll
    for (int n = 0; n < 4; ++n)
        bfofs[n] = (wc * 64 + n * 16 + lane16) * 64 + lgrp * 16;

    bf16x8 bf[2][4];
    #pragma unroll
    for (int n = 0; n < 4; ++n)                    // B(0) issued first
        bf[0][n] = *(const bf16x8*)(wbase + bfofs[n]);

    // ================= PHASE 1: linear A stream -> LDS =================
    // thread's j-th load: global byte gi = j*8192 + tid*16 within the
    // 128KB row-major f32 tile. row = j*4 + (tid>>7); within-row f32 = tid*4 & 511.
    {
        const int rlo  = tid >> 7;                 // 0..3
        const int cidx = (tid * 4) & 511;          // f32 index within row
        const int fg   = tid & 127;                // 8B-bf16 granule within row
        const int gsl  = fg >> 1;                  // 16B granule 0..63
        const int ghl  = (fg & 1) << 3;            // 8B half within granule
        f32x4 ra[16];
        #pragma unroll
        for (int j = 0; j < 16; ++j) {
            int r = bm * 64 + j * 4 + rlo;
            if (r > 99999) r = 99999;              // tail clamp (masked in K2)
            ra[j] = *(const f32x4*)(basis + (size_t)r * 512 + cidx);
        }
        #pragma unroll
        for (int j = 0; j < 16; ++j) {
            const int row = j * 4 + rlo;           // local row 0..63
            bf16x4 v;
            v[0] = (__bf16)ra[j][0]; v[1] = (__bf16)ra[j][1];
            v[2] = (__bf16)ra[j][2]; v[3] = (__bf16)ra[j][3];
            *(bf16x4*)(smem + row * 1024 + ((gsl ^ row) << 4) + ghl) = v;
        }
    }
    __syncthreads();                               // the ONLY K-loop barrier

    // ================= PHASE 2: free-running MFMA =================
    f32x4 acc[4][4] = {};
    #pragma unroll
    for (int t = 0; t < 16; ++t) {
        if (t < 15) {                              // B(t+1), depth-2 regs
            #pragma unroll
            for (int n = 0; n < 4; ++n)
                bf[(t + 1) & 1][n] =
                    *(const bf16x8*)(wbase + (size_t)(t + 1) * 32768 + bfofs[n]);
        }
        #pragma unroll
        for (int mh = 0; mh < 2; ++mh) {           // 2 frags at a time (VGPR)
            bf16x8 af[2];
            #pragma unroll
            for (int mi = 0; mi < 2; ++mi) {
                int rr = (mh * 2 + mi) * 16 + lane16;      // row 0..63
                af[mi] = *(const bf16x8*)(smem + rr * 1024
                           + (((t * 4 + lgrp) ^ rr) << 4));
            }
            __builtin_amdgcn_s_setprio(1);
            #pragma unroll
            for (int mi = 0; mi < 2; ++mi)
                #pragma unroll
                for (int n = 0; n < 4; ++n)
                    acc[mh * 2 + mi][n] = __builtin_amdgcn_mfma_f32_16x16x32_bf16(
                        af[mi], bf[t & 1][n], acc[mh * 2 + mi][n], 0, 0, 0);
            __builtin_amdgcn_s_setprio(0);
        }
    }

    // ---- epilogue: sign bytes -> LDS transpose -> multiply-pack -> u64 ----
    // C/D layout: col = lane&15, row = (lane>>4)*4 + reg
    __syncthreads();                               // A-tile reads done; alias sb
    unsigned char* sb = (unsigned char*)smem;      // [512 cols][68B] = 34.8KB
    #pragma unroll
    for (int m = 0; m < 4; ++m) {
        #pragma unroll
        for (int n = 0; n < 4; ++n) {
            int cc = wc * 64 + n * 16 + lane16;    // col 0..511
            int rb = m * 16 + lgrp * 4;            // row base 0..60
            uint32_t pk = 0;
            #pragma unroll
            for (int rg = 0; rg < 4; ++rg)
                pk |= (acc[m][n][rg] < 0.0f ? 1u : 0u) << (8 * rg);
            *(uint32_t*)&sb[cc * 68 + rb] = pk;
        }
    }
    __syncthreads();

    {   // one thread per column; 64 sign bytes -> u64; word index = bm
        const unsigned char* src = &sb[tid * 68];
        uint64_t wbits = 0;
        #pragma unroll
        for (int k = 0; k < 16; ++k) {
            uint32_t qv = *(const uint32_t*)&src[4 * k];
            uint32_t p4 = ((qv & 0x01010101u) * 0x10204080u) >> 28;
            wbits |= (uint64_t)p4 << (4 * k);
        }
        sbits[(size_t)bm * 512 + tid] = wbits;     // 4KB contiguous per block
    }
}

// ---------- K2: crossing masks from sign bits ----------
__global__ void crossing_masks(const uint64_t* __restrict__ sbits,
                               uint64_t* __restrict__ maskT) {
    const int w = blockIdx.x;       // 0..1562
    const int j = threadIdx.x;      // 0..255
    uint64_t s0r = sbits[(size_t)w * 512 + j];
    uint64_t s0p = sbits[(size_t)w * 512 + 256 + j];
    uint64_t s1r = sbits[(size_t)(w + 1) * 512 + j];
    uint64_t s1p = sbits[(size_t)(w + 1) * 512 + 256 + j];
    uint64_t cr = s0r ^ ((s0r >> 1) | (s1r << 63));
    uint64_t cp = s0p ^ ((s0p >> 1) | (s1p << 63));
    uint64_t m = cr & cp;
    if (w == NW - 1) m &= 0x7FFFFFFFull;    // 31 valid crossings in last word
    maskT[(size_t)w * 256 + j] = m;
}

// ---------- K3: pairwise AND-popcount ----------
__global__ void zero_out(float* __restrict__ out) {
    int i = blockIdx.x * 256 + threadIdx.x;
    if (i < 32640) out[i] = 0.0f;
}

__global__ void pair_popcount(const uint64_t* __restrict__ maskT,
                              float* __restrict__ out) {
    const int i = blockIdx.x;   // 0..255
    const int c = blockIdx.y;   // 0..7 word chunk
    const int j = threadIdx.x;  // 0..255
    if (j <= i) return;
    int w0 = c * 196;
    int w1 = w0 + 196; if (w1 > NW) w1 = NW;
    uint32_t sum = 0;
    #pragma unroll 4
    for (int w = w0; w < w1; ++w) {
        uint64_t mi = maskT[(size_t)w * 256 + i];   // block-uniform -> scalar
        uint64_t mj = maskT[(size_t)w * 256 + j];   // coalesced
        sum += (uint32_t)__popcll(mi & mj);
    }
    const size_t idx = (size_t)i * (2 * KDIM - i - 1) / 2 + (size_t)(j - i - 1);
    atomicAdd(&out[idx], (float)sum);   // exact-integer f32 adds -> deterministic
}

extern "C" void kernel_launch(void* const* d_in, const int* in_sizes, int n_in,
                              void* d_out, int out_size, void* d_ws, size_t ws_size,
                              hipStream_t stream) {
    const float* theta = (const float*)d_in[0];
    const float* basis = (const float*)d_in[1];
    const float* noise = (const float*)d_in[2];
    float* out = (float*)d_out;

    char* ws = (char*)d_ws;
    __bf16*   Wt    = (__bf16*)ws;                              // 512 KB, tile-major
    uint64_t* sbits = (uint64_t*)(ws + 524288);                 // 6.41 MB
    uint64_t* maskT = (uint64_t*)(ws + 524288 + (size_t)NWORDS * 512 * 8); // 3.2 MB

    hipLaunchKernelGGL(build_w,        dim3(1024),    dim3(256), 0, stream, theta, noise, Wt);
    hipLaunchKernelGGL(gemm_signs,     dim3(NWORDS),  dim3(512), 0, stream, basis, Wt, sbits);
    hipLaunchKernelGGL(crossing_masks, dim3(NW),      dim3(256), 0, stream, sbits, maskT);
    hipLaunchKernelGGL(zero_out,       dim3(128),     dim3(256), 0, stream, out);
    hipLaunchKernelGGL(pair_popcount,  dim3(KDIM, 8), dim3(256), 0, stream, maskT, out);
}